// Round 2
// baseline (149.445 us; speedup 1.0000x reference)
//
#include <hip/hip_runtime.h>
#include <math.h>

#define BB 512
#define LL 128
#define DD 256
#define NREST 127            // L-1
#define EPSN 1e-12f

#define TI 128               // i-tile and k-tile per score block
#define NBLK ((BB / TI) * BB)   // 2048 score blocks

typedef float f32x4 __attribute__((ext_vector_type(4)));
typedef int   i32x4 __attribute__((ext_vector_type(4)));
typedef int   i32x8 __attribute__((ext_vector_type(8)));

// async global->LDS, 16B per lane; LDS base wave-uniform (HW adds lane*16)
#define GLD16(gp, lp) __builtin_amdgcn_global_load_lds( \
    (const __attribute__((address_space(1))) void*)(gp), \
    (__attribute__((address_space(3))) void*)(lp), 16, 0, 0)

// ---- Kernel 1: norm + normalize + cvt fp8(e4m3), piece-swizzled rows ----
// 4 rows per wave: lane = (sub-row<<4) | piece. Each lane reads 64 B of fp32
// (4x float4, contiguous), 4-step 16-lane shuffle reduce for the norm, packs
// 16 fp8 bytes, and writes ONE 16 B piece at slot (piece ^ (r&15)) -- the
// same XOR swizzle score's 16x16x128 fragment reads rely on (conflict-free).
// Rf[b][r] holds row l=r+1; Rf[b][127] zeroed (pad). Block 0 zeroes tot/pos/ctr.
__global__ __launch_bounds__(256) void prep_kernel(const float* __restrict__ in,
                                                   unsigned char* __restrict__ Af,
                                                   unsigned char* __restrict__ Rf,
                                                   float* __restrict__ totpos,
                                                   unsigned* __restrict__ ctr) {
    if (blockIdx.x == 0) {
        ((f32x4*)totpos)[threadIdx.x] = (f32x4){0.f, 0.f, 0.f, 0.f};  // 1024 floats
        if (threadIdx.x == 0) *ctr = 0u;
    }
    int wid   = threadIdx.x >> 6;
    int lane  = threadIdx.x & 63;
    int sub   = lane >> 4;             // row within wave 0..3
    int piece = lane & 15;             // 16B output piece / 64B input chunk
    int row   = blockIdx.x * 16 + wid * 4 + sub;   // 0..65535
    int b     = row >> 7;
    int l     = row & 127;

    const float4* rp = (const float4*)(in + (size_t)row * DD) + piece * 4;
    float4 v0 = rp[0], v1 = rp[1], v2 = rp[2], v3 = rp[3];

    float ss = v0.x*v0.x + v0.y*v0.y + v0.z*v0.z + v0.w*v0.w
             + v1.x*v1.x + v1.y*v1.y + v1.z*v1.z + v1.w*v1.w
             + v2.x*v2.x + v2.y*v2.y + v2.z*v2.z + v2.w*v2.w
             + v3.x*v3.x + v3.y*v3.y + v3.z*v3.z + v3.w*v3.w;
    #pragma unroll
    for (int off = 8; off; off >>= 1) ss += __shfl_xor(ss, off);  // 16-lane group
    float sc = 1.0f / fmaxf(sqrtf(ss), EPSN);

    int d0 = __builtin_amdgcn_cvt_pk_fp8_f32(v0.x * sc, v0.y * sc, 0, false);
    d0     = __builtin_amdgcn_cvt_pk_fp8_f32(v0.z * sc, v0.w * sc, d0, true);
    int d1 = __builtin_amdgcn_cvt_pk_fp8_f32(v1.x * sc, v1.y * sc, 0, false);
    d1     = __builtin_amdgcn_cvt_pk_fp8_f32(v1.z * sc, v1.w * sc, d1, true);
    int d2 = __builtin_amdgcn_cvt_pk_fp8_f32(v2.x * sc, v2.y * sc, 0, false);
    d2     = __builtin_amdgcn_cvt_pk_fp8_f32(v2.z * sc, v2.w * sc, d2, true);
    int d3 = __builtin_amdgcn_cvt_pk_fp8_f32(v3.x * sc, v3.y * sc, 0, false);
    d3     = __builtin_amdgcn_cvt_pk_fp8_f32(v3.z * sc, v3.w * sc, d3, true);
    i32x4 val = (i32x4){d0, d1, d2, d3};

    if (l == 0) {
        *(i32x4*)(Af + (size_t)b * DD + ((piece ^ (b & 15)) << 4)) = val;
        *(i32x4*)(Rf + ((size_t)b * LL + 127) * DD + ((piece ^ 15) << 4)) =
            (i32x4){0, 0, 0, 0};       // pad row (key = 127&15 = 15)
    } else {
        int r = l - 1;
        *(i32x4*)(Rf + ((size_t)b * LL + r) * DD + ((piece ^ (r & 15)) << 4)) = val;
    }
}

// ------- Kernel 2: MX-scaled fp8 MFMA (K=128, unit scales) + exp + k-sum -------
// Block: 128 anchors x 128 rest rows of batch j. Full K=256 staged upfront
// (64 KB LDS, pure linear 1KB-chunk copy since swizzle is baked into the
// global layout), ONE barrier, 32 MFMA/wave, then branch-free exp epilogue
// (pad k=127 contributes exp(0)=1, cancelled by a -1 init on its owner lane),
// per-i sums, device atomicAdd, and a fused last-block final reduction.
__global__ __launch_bounds__(256) void score_kernel(const unsigned char* __restrict__ Af,
                                                    const unsigned char* __restrict__ Rf,
                                                    const int* __restrict__ label,
                                                    float* __restrict__ tot,
                                                    float* __restrict__ pos,
                                                    unsigned* __restrict__ ctr,
                                                    float* __restrict__ out) {
    __shared__ unsigned char sA[TI * DD];   // 32 KB (swizzled rows, linear copy)
    __shared__ unsigned char sR[TI * DD];   // 32 KB
    __shared__ float         sP[TI * 2];
    __shared__ bool          lastBlk;
    __shared__ float         sw[4];

    const int tid  = threadIdx.x;
    const int i0   = blockIdx.x * TI;
    const int j    = blockIdx.y;

    const int lane = tid & 63;
    const int w    = tid >> 6;
    const int wm   = w & 1;            // wave row (i half)
    const int wn   = w >> 1;           // wave col (k_rest half)
    const int rowf = lane & 15;
    const int quad = lane >> 4;

    const unsigned char* aBase = Af + (size_t)i0 * DD;
    const unsigned char* rBase = Rf + (size_t)j * LL * DD;

    // ---- stage ALL of K: 64 x 1KB linear async copies, one barrier ----
    #pragma unroll
    for (int t = 0; t < 8; ++t) {
        int c = w * 8 + t;             // 1KB chunk 0..31 (4 rows each)
        GLD16(aBase + (size_t)c * 1024 + lane * 16, &sA[c * 1024]);
        GLD16(rBase + (size_t)c * 1024 + lane * 16, &sR[c * 1024]);
    }

    f32x4 acc[4][4];
    #pragma unroll
    for (int a = 0; a < 4; ++a)
        #pragma unroll
        for (int b = 0; b < 4; ++b) acc[a][b] = (f32x4){0.f, 0.f, 0.f, 0.f};

    __syncthreads();

    // ---- 2 K-steps of 128, 16 MFMA each; fragment reads conflict-free ----
    // A/B frag (16x16x128 f8f6f4): row/col = lane&15, k = quad*32 + byte.
    // Piece indices ks*8 + quad*2 {+1}; stored at slot (piece ^ rowf).
    #pragma unroll
    for (int ks = 0; ks < 2; ++ks) {
        const int o0 = (((ks * 8 + quad * 2) ^ rowf) << 4);
        const int o1 = o0 ^ 16;        // slot of piece+1 (base piece is even)
        i32x8 af[4], bf[4];
        #pragma unroll
        for (int mt = 0; mt < 4; ++mt) {
            const unsigned char* rp = &sA[(wm * 64 + mt * 16 + rowf) * DD];
            i32x4 lo = *(const i32x4*)(rp + o0);
            i32x4 hi = *(const i32x4*)(rp + o1);
            af[mt] = __builtin_shufflevector(lo, hi, 0, 1, 2, 3, 4, 5, 6, 7);
        }
        #pragma unroll
        for (int nt = 0; nt < 4; ++nt) {
            const unsigned char* rp = &sR[(wn * 64 + nt * 16 + rowf) * DD];
            i32x4 lo = *(const i32x4*)(rp + o0);
            i32x4 hi = *(const i32x4*)(rp + o1);
            bf[nt] = __builtin_shufflevector(lo, hi, 0, 1, 2, 3, 4, 5, 6, 7);
        }
        #pragma unroll
        for (int mt = 0; mt < 4; ++mt)
            #pragma unroll
            for (int nt = 0; nt < 4; ++nt)
                acc[mt][nt] = __builtin_amdgcn_mfma_scale_f32_16x16x128_f8f6f4(
                    af[mt], bf[nt], acc[mt][nt],
                    0, 0,                 // cbsz=fp8(e4m3), blgp=fp8(e4m3)
                    0, 0x7f7f7f7f,        // scale A: e8m0 127 -> x1.0
                    0, 0x7f7f7f7f);       // scale B: x1.0
    }

    // ---- epilogue: exp + sum over this wave's 64 k values, branch-free ----
    // C/D layout: col(n) = lane&15, row(m) = quad*4 + reg (verified).
    // k index n = wn*64 + nt*16 + rowf; the pad k=127 (wn=1,nt=3,rowf=15)
    // contributes exp(0)=1 -> cancel with a -1.0 initial on that lane.
    const float sinit = (wn == 1 && rowf == 15) ? -1.0f : 0.0f;
    #pragma unroll
    for (int mt = 0; mt < 4; ++mt) {
        float s[4];
        #pragma unroll
        for (int r = 0; r < 4; ++r) s[r] = sinit;
        #pragma unroll
        for (int nt = 0; nt < 4; ++nt) {
            #pragma unroll
            for (int r = 0; r < 4; ++r)
                s[r] += __expf(acc[mt][nt][r]);
        }
        #pragma unroll
        for (int r = 0; r < 4; ++r) {
            #pragma unroll
            for (int off = 1; off < 16; off <<= 1) s[r] += __shfl_xor(s[r], off);
        }
        if (rowf == 0) {
            #pragma unroll
            for (int r = 0; r < 4; ++r)
                sP[(wm * 64 + mt * 16 + quad * 4 + r) * 2 + wn] = s[r];
        }
    }
    __syncthreads();
    if (tid < TI) {
        int i = i0 + tid;
        float e = sP[tid * 2] + sP[tid * 2 + 1];
        atomicAdd(&tot[i], e);
        if (label[j] == label[i]) atomicAdd(&pos[i], e);
    }

    // ---- fused final: last finishing block computes the loss ----
    __syncthreads();                    // all this block's atomics issued+drained
    if (tid == 0) {
        __threadfence();
        unsigned old = atomicAdd(ctr, 1u);
        lastBlk = (old == (unsigned)(NBLK - 1));
    }
    __syncthreads();
    if (lastBlk) {
        int t0 = tid, t1 = tid + 256;
        // atomic RMW readback: coherent across XCDs regardless of L2 state
        float a0 = atomicAdd(&tot[t0], 0.0f), p0 = atomicAdd(&pos[t0], 0.0f);
        float a1 = atomicAdd(&tot[t1], 0.0f), p1 = atomicAdd(&pos[t1], 0.0f);
        float s = (logf(a0) - logf(p0)) + (logf(a1) - logf(p1));
        #pragma unroll
        for (int off = 32; off; off >>= 1) s += __shfl_xor(s, off);
        if (lane == 0) sw[w] = s;
        __syncthreads();
        if (tid == 0) out[0] = (sw[0] + sw[1] + sw[2] + sw[3]) * (1.0f / BB);
    }
}

extern "C" void kernel_launch(void* const* d_in, const int* in_sizes, int n_in,
                              void* d_out, int out_size, void* d_ws, size_t ws_size,
                              hipStream_t stream) {
    const float* in    = (const float*)d_in[0];
    const int*   label = (const int*)d_in[1];
    float*       out   = (float*)d_out;

    unsigned char* Af  = (unsigned char*)d_ws;               // 512*256 B (128 KB)
    unsigned char* Rf  = Af + (size_t)BB * DD;               // 512*128*256 B (16 MB)
    float*         tot = (float*)(Rf + (size_t)BB * LL * DD); // 512 f32
    float*         pos = tot + BB;                            // 512 f32
    unsigned*      ctr = (unsigned*)(pos + BB);               // completion counter

    prep_kernel<<<(BB * LL) / 16, 256, 0, stream>>>(in, Af, Rf, tot, ctr);
    score_kernel<<<dim3(BB / TI, BB), 256, 0, stream>>>(Af, Rf, label, tot, pos, ctr, out);
}

// Round 3
// 136.505 us; speedup vs baseline: 1.0948x; 1.0948x over previous
//
#include <hip/hip_runtime.h>
#include <math.h>

#define BB 512
#define LL 128
#define DD 256
#define EPSN 1e-12f

typedef float f32x4 __attribute__((ext_vector_type(4)));
typedef int   i32x4 __attribute__((ext_vector_type(4)));
typedef int   i32x8 __attribute__((ext_vector_type(8)));

// async global->LDS, 16B per lane; LDS base wave-uniform (HW adds lane*16)
#define GLD16(gp, lp) __builtin_amdgcn_global_load_lds( \
    (const __attribute__((address_space(1))) void*)(gp), \
    (__attribute__((address_space(3))) void*)(lp), 16, 0, 0)

// ---- Kernel 1: norm + normalize + cvt fp8(e4m3), piece-swizzled rows ----
// 4 rows per wave: lane = (sub-row<<4) | piece. Each lane reads 64 B of fp32
// (4x float4 contiguous), 4-step 16-lane shuffle reduce for the norm, packs
// 16 fp8 bytes, writes ONE 16 B piece at slot (piece ^ (r&15)) -- the XOR
// swizzle score's 16x16x128 fragment reads rely on (bank-conflict-free,
// verified SQ_LDS_BANK_CONFLICT==0). Rf[b][r] holds row l=r+1; Rf[b][127]
// zeroed (pad, key 127&15=15). Block 0 zeroes the output scalar.
__global__ __launch_bounds__(256) void prep_kernel(const float* __restrict__ in,
                                                   unsigned char* __restrict__ Af,
                                                   unsigned char* __restrict__ Rf,
                                                   float* __restrict__ out) {
    if (blockIdx.x == 0 && threadIdx.x == 0) out[0] = 0.0f;
    int wid   = threadIdx.x >> 6;
    int lane  = threadIdx.x & 63;
    int sub   = lane >> 4;             // row within wave 0..3
    int piece = lane & 15;             // 16B output piece / 64B input chunk
    int row   = blockIdx.x * 16 + wid * 4 + sub;   // 0..65535
    int b     = row >> 7;
    int l     = row & 127;

    const float4* rp = (const float4*)(in + (size_t)row * DD) + piece * 4;
    float4 v0 = rp[0], v1 = rp[1], v2 = rp[2], v3 = rp[3];

    float ss = v0.x*v0.x + v0.y*v0.y + v0.z*v0.z + v0.w*v0.w
             + v1.x*v1.x + v1.y*v1.y + v1.z*v1.z + v1.w*v1.w
             + v2.x*v2.x + v2.y*v2.y + v2.z*v2.z + v2.w*v2.w
             + v3.x*v3.x + v3.y*v3.y + v3.z*v3.z + v3.w*v3.w;
    #pragma unroll
    for (int off = 8; off; off >>= 1) ss += __shfl_xor(ss, off);  // 16-lane group
    float sc = 1.0f / fmaxf(sqrtf(ss), EPSN);

    int d0 = __builtin_amdgcn_cvt_pk_fp8_f32(v0.x * sc, v0.y * sc, 0, false);
    d0     = __builtin_amdgcn_cvt_pk_fp8_f32(v0.z * sc, v0.w * sc, d0, true);
    int d1 = __builtin_amdgcn_cvt_pk_fp8_f32(v1.x * sc, v1.y * sc, 0, false);
    d1     = __builtin_amdgcn_cvt_pk_fp8_f32(v1.z * sc, v1.w * sc, d1, true);
    int d2 = __builtin_amdgcn_cvt_pk_fp8_f32(v2.x * sc, v2.y * sc, 0, false);
    d2     = __builtin_amdgcn_cvt_pk_fp8_f32(v2.z * sc, v2.w * sc, d2, true);
    int d3 = __builtin_amdgcn_cvt_pk_fp8_f32(v3.x * sc, v3.y * sc, 0, false);
    d3     = __builtin_amdgcn_cvt_pk_fp8_f32(v3.z * sc, v3.w * sc, d3, true);
    i32x4 val = (i32x4){d0, d1, d2, d3};

    if (l == 0) {
        *(i32x4*)(Af + (size_t)b * DD + ((piece ^ (b & 15)) << 4)) = val;
        *(i32x4*)(Rf + ((size_t)b * LL + 127) * DD + ((piece ^ 15) << 4)) =
            (i32x4){0, 0, 0, 0};       // pad row
    } else {
        int r = l - 1;
        *(i32x4*)(Rf + ((size_t)b * LL + r) * DD + ((piece ^ (r & 15)) << 4)) = val;
    }
}

// ------- Kernel 2: MX-scaled fp8 MFMA (K=128, unit scales) + exp + k-sum -------
// 64x64 tile, k split in halves: 8192 blocks, 33 KB LDS -> 4 blocks/CU
// (16 waves/CU, 2x the latency hiding of the 64KB version). 1-D block id is
// XCD-swizzled so all 16 blocks sharing Rf[j] run on XCD (wg&7): R re-reads
// are L2-local. No atomics: each block writes a 256 B coalesced partial row.
__global__ __launch_bounds__(256) void score_kernel(const unsigned char* __restrict__ Af,
                                                    const unsigned char* __restrict__ Rf,
                                                    float* __restrict__ partial) {
    __shared__ unsigned char sA[64 * DD];   // 16 KB (swizzled rows, linear copy)
    __shared__ unsigned char sR[64 * DD];   // 16 KB
    __shared__ float         sP[64 * 2];

    const int tid  = threadIdx.x;
    // XCD-locality decode: XCD (wg&7) owns j in [64*xcd, 64*xcd+64)
    const unsigned wg   = blockIdx.x;
    const int      xcd  = wg & 7;
    const int      slot = wg >> 3;          // 0..1023
    const int      j    = xcd * 64 + (slot >> 4);
    const int      subb = slot & 15;
    const int      bix  = subb >> 1;        // i-tile 0..7
    const int      kh   = subb & 1;         // k-half 0..1
    const int      i0   = bix * 64;

    const int lane = tid & 63;
    const int w    = tid >> 6;
    const int wm   = w & 1;            // wave i-half (32)
    const int wn   = w >> 1;           // wave k-half (32)
    const int rowf = lane & 15;
    const int quad = lane >> 4;

    const unsigned char* aBase = Af + (size_t)i0 * DD;
    const unsigned char* rBase = Rf + ((size_t)j * LL + kh * 64) * DD;

    // ---- stage 32 KB: 32 x 1KB linear async copies, one barrier ----
    #pragma unroll
    for (int t = 0; t < 4; ++t) {
        int c = w * 4 + t;             // 1KB chunk 0..15 (4 rows each)
        GLD16(aBase + (size_t)c * 1024 + lane * 16, &sA[c * 1024]);
        GLD16(rBase + (size_t)c * 1024 + lane * 16, &sR[c * 1024]);
    }

    f32x4 acc[2][2];
    #pragma unroll
    for (int a = 0; a < 2; ++a)
        #pragma unroll
        for (int b = 0; b < 2; ++b) acc[a][b] = (f32x4){0.f, 0.f, 0.f, 0.f};

    __syncthreads();

    // ---- 2 K-steps of 128, 4 MFMA each; fragment reads conflict-free ----
    // A/B frag (16x16x128 f8f6f4): row/col = lane&15, k = quad*32 + byte.
    // Piece indices ks*8 + quad*2 {+1}; stored at slot (piece ^ (row&15)).
    #pragma unroll
    for (int ks = 0; ks < 2; ++ks) {
        const int o0 = (((ks * 8 + quad * 2) ^ rowf) << 4);
        const int o1 = o0 ^ 16;        // slot of piece+1 (base piece is even)
        i32x8 af[2], bf[2];
        #pragma unroll
        for (int mt = 0; mt < 2; ++mt) {
            const unsigned char* rp = &sA[(wm * 32 + mt * 16 + rowf) * DD];
            i32x4 lo = *(const i32x4*)(rp + o0);
            i32x4 hi = *(const i32x4*)(rp + o1);
            af[mt] = __builtin_shufflevector(lo, hi, 0, 1, 2, 3, 4, 5, 6, 7);
        }
        #pragma unroll
        for (int nt = 0; nt < 2; ++nt) {
            const unsigned char* rp = &sR[(wn * 32 + nt * 16 + rowf) * DD];
            i32x4 lo = *(const i32x4*)(rp + o0);
            i32x4 hi = *(const i32x4*)(rp + o1);
            bf[nt] = __builtin_shufflevector(lo, hi, 0, 1, 2, 3, 4, 5, 6, 7);
        }
        #pragma unroll
        for (int mt = 0; mt < 2; ++mt)
            #pragma unroll
            for (int nt = 0; nt < 2; ++nt)
                acc[mt][nt] = __builtin_amdgcn_mfma_scale_f32_16x16x128_f8f6f4(
                    af[mt], bf[nt], acc[mt][nt],
                    0, 0,                 // cbsz=fp8(e4m3), blgp=fp8(e4m3)
                    0, 0x7f7f7f7f,        // scale A: e8m0 127 -> x1.0
                    0, 0x7f7f7f7f);       // scale B: x1.0
    }

    // ---- epilogue: exp + sum over this wave's 32 k values, branch-free ----
    // C/D layout: col(n)=lane&15, row(m)=quad*4+reg (verified). Global k =
    // kh*64 + wn*32 + nt*16 + rowf; pad k=127 (kh=1,wn=1,nt=1,rowf=15)
    // contributes exp(0)=1 -> cancel with -1.0 init on its owner lane.
    const float sinit = (kh == 1 && wn == 1 && rowf == 15) ? -1.0f : 0.0f;
    #pragma unroll
    for (int mt = 0; mt < 2; ++mt) {
        float s[4];
        #pragma unroll
        for (int r = 0; r < 4; ++r) s[r] = sinit;
        #pragma unroll
        for (int nt = 0; nt < 2; ++nt) {
            #pragma unroll
            for (int r = 0; r < 4; ++r)
                s[r] += __expf(acc[mt][nt][r]);
        }
        #pragma unroll
        for (int r = 0; r < 4; ++r) {
            #pragma unroll
            for (int off = 1; off < 16; off <<= 1) s[r] += __shfl_xor(s[r], off);
        }
        if (rowf == 0) {
            #pragma unroll
            for (int r = 0; r < 4; ++r)
                sP[(wm * 32 + mt * 16 + quad * 4 + r) * 2 + wn] = s[r];
        }
    }
    __syncthreads();
    if (tid < 64) {
        float e = sP[tid * 2] + sP[tid * 2 + 1];
        partial[((size_t)j * 2 + kh) * BB + i0 + tid] = e;   // coalesced, no atomics
    }
}

// ---- Kernel 3: tot/pos reduction over 1024 partial rows + loss ----
// 8 blocks x 64 i's. Wave w handles jk-stripe [w*256, w*256+256); loads are
// 256 B coalesced per wave-iter; 4-deep ILP accumulators hide L2 latency.
__global__ __launch_bounds__(256) void final_kernel(const float* __restrict__ partial,
                                                    const int* __restrict__ label,
                                                    float* __restrict__ out) {
    __shared__ float sT[4][64], sQ[4][64];
    const int il = threadIdx.x & 63;
    const int w  = threadIdx.x >> 6;
    const int i  = blockIdx.x * 64 + il;
    const int myLab = label[i];

    float t0 = 0.f, t1 = 0.f, t2 = 0.f, t3 = 0.f;
    float p0 = 0.f, p1 = 0.f, p2 = 0.f, p3 = 0.f;
    const float* base = partial + (size_t)(w * 256) * BB + i;
    #pragma unroll 1
    for (int jj = 0; jj < 256; jj += 4) {
        float v0 = base[(size_t)(jj + 0) * BB];
        float v1 = base[(size_t)(jj + 1) * BB];
        float v2 = base[(size_t)(jj + 2) * BB];
        float v3 = base[(size_t)(jj + 3) * BB];
        int jk = w * 256 + jj;
        int l0 = label[(jk + 0) >> 1], l1 = label[(jk + 1) >> 1];
        int l2 = label[(jk + 2) >> 1], l3 = label[(jk + 3) >> 1];
        t0 += v0; t1 += v1; t2 += v2; t3 += v3;
        if (l0 == myLab) p0 += v0;
        if (l1 == myLab) p1 += v1;
        if (l2 == myLab) p2 += v2;
        if (l3 == myLab) p3 += v3;
    }
    sT[w][il] = (t0 + t1) + (t2 + t3);
    sQ[w][il] = (p0 + p1) + (p2 + p3);
    __syncthreads();
    if (w == 0) {
        float tt = (sT[0][il] + sT[1][il]) + (sT[2][il] + sT[3][il]);
        float pp = (sQ[0][il] + sQ[1][il]) + (sQ[2][il] + sQ[3][il]);
        float s = (logf(tt) - logf(pp)) * (1.0f / BB);
        #pragma unroll
        for (int off = 32; off; off >>= 1) s += __shfl_xor(s, off);
        if (il == 0) atomicAdd(out, s);   // 8 adds total, device scope
    }
}

extern "C" void kernel_launch(void* const* d_in, const int* in_sizes, int n_in,
                              void* d_out, int out_size, void* d_ws, size_t ws_size,
                              hipStream_t stream) {
    const float* in    = (const float*)d_in[0];
    const int*   label = (const int*)d_in[1];
    float*       out   = (float*)d_out;

    unsigned char* Af      = (unsigned char*)d_ws;                // 128 KB
    unsigned char* Rf      = Af + (size_t)BB * DD;                // 16 MB
    float*         partial = (float*)(Rf + (size_t)BB * LL * DD); // 1024*512 f32 (2 MB)

    prep_kernel<<<(BB * LL) / 16, 256, 0, stream>>>(in, Af, Rf, out);
    score_kernel<<<(BB / 64) * BB * 2, 256, 0, stream>>>(Af, Rf, partial);
    final_kernel<<<BB / 64, 256, 0, stream>>>(partial, label, out);
}

// Round 4
// 114.295 us; speedup vs baseline: 1.3075x; 1.1943x over previous
//
#include <hip/hip_runtime.h>
#include <math.h>

#define BB 512
#define LL 128
#define DD 256
#define EPSN 1e-12f

#define TI 128               // i-tile and k-tile per score block

typedef float f32x4 __attribute__((ext_vector_type(4)));
typedef int   i32x4 __attribute__((ext_vector_type(4)));
typedef int   i32x8 __attribute__((ext_vector_type(8)));

// async global->LDS, 16B per lane; LDS base wave-uniform (HW adds lane*16)
#define GLD16(gp, lp) __builtin_amdgcn_global_load_lds( \
    (const __attribute__((address_space(1))) void*)(gp), \
    (__attribute__((address_space(3))) void*)(lp), 16, 0, 0)

// ---- Kernel 1: norm + normalize + cvt fp8(e4m3), piece-swizzled rows ----
// 4 rows per wave: lane = (sub-row<<4) | piece. Each lane reads 64 B of fp32
// (4x float4 contiguous), 4-step 16-lane shuffle reduce for the norm, packs
// 16 fp8 bytes, writes ONE 16 B piece at slot (piece ^ (r&15)) -- the XOR
// swizzle score's 16x16x128 fragment reads rely on (bank-conflict-free,
// verified SQ_LDS_BANK_CONFLICT==0). Rf[b][r] holds row l=r+1; Rf[b][127]
// zeroed (pad, key 127&15=15). Block 0 zeroes tot/pos.
__global__ __launch_bounds__(256) void prep_kernel(const float* __restrict__ in,
                                                   unsigned char* __restrict__ Af,
                                                   unsigned char* __restrict__ Rf,
                                                   float* __restrict__ totpos) {
    if (blockIdx.x == 0) {
        ((f32x4*)totpos)[threadIdx.x] = (f32x4){0.f, 0.f, 0.f, 0.f};  // 1024 floats
    }
    int wid   = threadIdx.x >> 6;
    int lane  = threadIdx.x & 63;
    int sub   = lane >> 4;             // row within wave 0..3
    int piece = lane & 15;             // 16B output piece / 64B input chunk
    int row   = blockIdx.x * 16 + wid * 4 + sub;   // 0..65535
    int b     = row >> 7;
    int l     = row & 127;

    const float4* rp = (const float4*)(in + (size_t)row * DD) + piece * 4;
    float4 v0 = rp[0], v1 = rp[1], v2 = rp[2], v3 = rp[3];

    float ss = v0.x*v0.x + v0.y*v0.y + v0.z*v0.z + v0.w*v0.w
             + v1.x*v1.x + v1.y*v1.y + v1.z*v1.z + v1.w*v1.w
             + v2.x*v2.x + v2.y*v2.y + v2.z*v2.z + v2.w*v2.w
             + v3.x*v3.x + v3.y*v3.y + v3.z*v3.z + v3.w*v3.w;
    #pragma unroll
    for (int off = 8; off; off >>= 1) ss += __shfl_xor(ss, off);  // 16-lane group
    float sc = 1.0f / fmaxf(sqrtf(ss), EPSN);

    int d0 = __builtin_amdgcn_cvt_pk_fp8_f32(v0.x * sc, v0.y * sc, 0, false);
    d0     = __builtin_amdgcn_cvt_pk_fp8_f32(v0.z * sc, v0.w * sc, d0, true);
    int d1 = __builtin_amdgcn_cvt_pk_fp8_f32(v1.x * sc, v1.y * sc, 0, false);
    d1     = __builtin_amdgcn_cvt_pk_fp8_f32(v1.z * sc, v1.w * sc, d1, true);
    int d2 = __builtin_amdgcn_cvt_pk_fp8_f32(v2.x * sc, v2.y * sc, 0, false);
    d2     = __builtin_amdgcn_cvt_pk_fp8_f32(v2.z * sc, v2.w * sc, d2, true);
    int d3 = __builtin_amdgcn_cvt_pk_fp8_f32(v3.x * sc, v3.y * sc, 0, false);
    d3     = __builtin_amdgcn_cvt_pk_fp8_f32(v3.z * sc, v3.w * sc, d3, true);
    i32x4 val = (i32x4){d0, d1, d2, d3};

    if (l == 0) {
        *(i32x4*)(Af + (size_t)b * DD + ((piece ^ (b & 15)) << 4)) = val;
        *(i32x4*)(Rf + ((size_t)b * LL + 127) * DD + ((piece ^ 15) << 4)) =
            (i32x4){0, 0, 0, 0};       // pad row
    } else {
        int r = l - 1;
        *(i32x4*)(Rf + ((size_t)b * LL + r) * DD + ((piece ^ (r & 15)) << 4)) = val;
    }
}

// ------- Kernel 2: MX-scaled fp8 MFMA (K=128, unit scales) + exp + k-sum -------
// R1 structure (128 anchors x 128 rest rows, full K=256 staged upfront, one
// barrier) but with 512-thread blocks: same 64 KB LDS and same total traffic,
// 2 blocks/CU x 8 waves = 16 waves/CU (2x R1's latency hiding). Per wave:
// 16 MFMA (16x16x128 f8f6f4, unit scales), branch-free exp epilogue (pad
// k=127 contributes exp(0)=1, cancelled by -1 init), per-i sums, atomicAdd.
__global__ __launch_bounds__(512, 4) void score_kernel(const unsigned char* __restrict__ Af,
                                                       const unsigned char* __restrict__ Rf,
                                                       const int* __restrict__ label,
                                                       float* __restrict__ tot,
                                                       float* __restrict__ pos) {
    __shared__ unsigned char sA[TI * DD];   // 32 KB (swizzled rows, linear copy)
    __shared__ unsigned char sR[TI * DD];   // 32 KB
    __shared__ float         sP[TI * 2];

    const int tid  = threadIdx.x;
    const int i0   = blockIdx.x * TI;
    const int j    = blockIdx.y;

    const int lane = tid & 63;
    const int w    = tid >> 6;         // 0..7
    const int wm   = w & 3;            // i-quarter (32 rows)
    const int wn   = w >> 2;           // k-half (64 cols)
    const int rowf = lane & 15;
    const int quad = lane >> 4;

    const unsigned char* aBase = Af + (size_t)i0 * DD;
    const unsigned char* rBase = Rf + (size_t)j * LL * DD;

    // ---- stage ALL of K: 64 x 1KB linear async copies, one barrier ----
    #pragma unroll
    for (int t = 0; t < 4; ++t) {
        int c = w * 4 + t;             // 1KB chunk 0..31 (4 rows each)
        GLD16(aBase + (size_t)c * 1024 + lane * 16, &sA[c * 1024]);
        GLD16(rBase + (size_t)c * 1024 + lane * 16, &sR[c * 1024]);
    }

    f32x4 acc[2][4];
    #pragma unroll
    for (int a = 0; a < 2; ++a)
        #pragma unroll
        for (int b = 0; b < 4; ++b) acc[a][b] = (f32x4){0.f, 0.f, 0.f, 0.f};

    __syncthreads();

    // ---- 2 K-steps of 128, 8 MFMA each; fragment reads conflict-free ----
    // A/B frag (16x16x128 f8f6f4): row/col = lane&15, k = quad*32 + byte.
    // Piece indices ks*8 + quad*2 {+1}; stored at slot (piece ^ (row&15)).
    #pragma unroll
    for (int ks = 0; ks < 2; ++ks) {
        const int o0 = (((ks * 8 + quad * 2) ^ rowf) << 4);
        const int o1 = o0 ^ 16;        // slot of piece+1 (base piece is even)
        i32x8 af[2], bf[4];
        #pragma unroll
        for (int mt = 0; mt < 2; ++mt) {
            const unsigned char* rp = &sA[(wm * 32 + mt * 16 + rowf) * DD];
            i32x4 lo = *(const i32x4*)(rp + o0);
            i32x4 hi = *(const i32x4*)(rp + o1);
            af[mt] = __builtin_shufflevector(lo, hi, 0, 1, 2, 3, 4, 5, 6, 7);
        }
        #pragma unroll
        for (int nt = 0; nt < 4; ++nt) {
            const unsigned char* rp = &sR[(wn * 64 + nt * 16 + rowf) * DD];
            i32x4 lo = *(const i32x4*)(rp + o0);
            i32x4 hi = *(const i32x4*)(rp + o1);
            bf[nt] = __builtin_shufflevector(lo, hi, 0, 1, 2, 3, 4, 5, 6, 7);
        }
        #pragma unroll
        for (int mt = 0; mt < 2; ++mt)
            #pragma unroll
            for (int nt = 0; nt < 4; ++nt)
                acc[mt][nt] = __builtin_amdgcn_mfma_scale_f32_16x16x128_f8f6f4(
                    af[mt], bf[nt], acc[mt][nt],
                    0, 0,                 // cbsz=fp8(e4m3), blgp=fp8(e4m3)
                    0, 0x7f7f7f7f,        // scale A: e8m0 127 -> x1.0
                    0, 0x7f7f7f7f);       // scale B: x1.0
    }

    // ---- epilogue: exp + sum over this wave's 64 k values, branch-free ----
    // C/D layout: col(n)=lane&15, row(m)=quad*4+reg (verified). Global k =
    // wn*64 + nt*16 + rowf; pad k=127 (wn=1,nt=3,rowf=15) contributes
    // exp(0)=1 -> cancel with -1.0 init on its owner lane (once per i-row).
    const float sinit = (wn == 1 && rowf == 15) ? -1.0f : 0.0f;
    #pragma unroll
    for (int mt = 0; mt < 2; ++mt) {
        float s[4];
        #pragma unroll
        for (int r = 0; r < 4; ++r) s[r] = sinit;
        #pragma unroll
        for (int nt = 0; nt < 4; ++nt) {
            #pragma unroll
            for (int r = 0; r < 4; ++r)
                s[r] += __expf(acc[mt][nt][r]);
        }
        #pragma unroll
        for (int r = 0; r < 4; ++r) {
            #pragma unroll
            for (int off = 1; off < 16; off <<= 1) s[r] += __shfl_xor(s[r], off);
        }
        if (rowf == 0) {
            #pragma unroll
            for (int r = 0; r < 4; ++r)
                sP[(wm * 32 + mt * 16 + quad * 4 + r) * 2 + wn] = s[r];
        }
    }
    __syncthreads();
    if (tid < TI) {
        int i = i0 + tid;
        float e = sP[tid * 2] + sP[tid * 2 + 1];
        atomicAdd(&tot[i], e);
        if (label[j] == label[i]) atomicAdd(&pos[i], e);
    }
}

// ---- Kernel 3: loss = mean_i( log tot[i] - log pos[i] ) ----
__global__ __launch_bounds__(256) void final_kernel(const float* __restrict__ tot,
                                                    const float* __restrict__ pos,
                                                    float* __restrict__ out) {
    int t0 = threadIdx.x, t1 = threadIdx.x + 256;
    float s = (logf(tot[t0]) - logf(pos[t0])) + (logf(tot[t1]) - logf(pos[t1]));
    #pragma unroll
    for (int off = 32; off; off >>= 1) s += __shfl_xor(s, off);
    __shared__ float sw[4];
    int wid = threadIdx.x >> 6;
    if ((threadIdx.x & 63) == 0) sw[wid] = s;
    __syncthreads();
    if (threadIdx.x == 0) out[0] = (sw[0] + sw[1] + sw[2] + sw[3]) * (1.0f / BB);
}

extern "C" void kernel_launch(void* const* d_in, const int* in_sizes, int n_in,
                              void* d_out, int out_size, void* d_ws, size_t ws_size,
                              hipStream_t stream) {
    const float* in    = (const float*)d_in[0];
    const int*   label = (const int*)d_in[1];
    float*       out   = (float*)d_out;

    unsigned char* Af  = (unsigned char*)d_ws;               // 512*256 B (128 KB)
    unsigned char* Rf  = Af + (size_t)BB * DD;               // 512*128*256 B (16 MB)
    float*         tot = (float*)(Rf + (size_t)BB * LL * DD); // 512 f32
    float*         pos = tot + BB;                            // 512 f32

    prep_kernel<<<(BB * LL) / 16, 256, 0, stream>>>(in, Af, Rf, tot);
    score_kernel<<<dim3(BB / TI, BB), 512, 0, stream>>>(Af, Rf, label, tot, pos);
    final_kernel<<<1, 256, 0, stream>>>(tot, pos, out);
}